// Round 5
// baseline (482.042 us; speedup 1.0000x reference)
//
#include <hip/hip_runtime.h>
#include <hip/hip_bf16.h>
#include <math.h>

#define B_TOT 262144

typedef __attribute__((ext_vector_type(8))) short v8s;
typedef __attribute__((ext_vector_type(4))) float v4f;

// ws layout (bf16 element offsets):
//  W1 frag-order   [0, 20480)        (8 n-tiles x 5 k-chunks x 512)
//  W2 frag-order   [20480, 36864)    (8 x 4 x 512)
//  Wf frag-order   [36864, 53248)    (8 x 4 x 512)
//  seen frag-order [53248, 67584)    (7 x 4 x 512, rows >=100 zero-padded)
//  s2 (fp32)       byte offset 135168, 112 floats (1e30 for pad rows)
#define WS_W1 0
#define WS_W2 20480
#define WS_WF 36864
#define WS_SEEN 53248
#define WS_S2_BYTES 135168

#define MFMA __builtin_amdgcn_mfma_f32_16x16x32_bf16

__device__ __forceinline__ unsigned short f2bf(float f) {
  union { float f; unsigned u; } cv; cv.f = f;
  unsigned u = cv.u;
  return (unsigned short)((u + 0x7FFFu + ((u >> 16) & 1u)) >> 16);  // RNE
}
__device__ __forceinline__ float bf2f(unsigned short h) {
  union { unsigned u; float f; } cv; cv.u = ((unsigned)h) << 16;
  return cv.f;
}
// packed RNE f32x2 -> bf16x2 (v_cvt_pk_bf16_f32 on gfx950); low 16 = x
__device__ __forceinline__ unsigned f2bf2(float x, float y) {
  float2 f; f.x = x; f.y = y;
  __hip_bfloat162 h = __float22bfloat162_rn(f);
  union { __hip_bfloat162 h; unsigned u; } cv; cv.h = h;
  return cv.u;
}

// Repack weights to bf16 in MFMA B-fragment-linear order.
// B-frag for (tile t, k-chunk c): lane L holds B[n = t*16 + (L&15)][k = c*32 + (L>>4)*8 + j]
__global__ void curiosity_prep(const float* __restrict__ W1, const float* __restrict__ W2,
                               const float* __restrict__ Wf, const float* __restrict__ seen,
                               unsigned short* __restrict__ wsb, float* __restrict__ s2) {
  int bid = blockIdx.x;
  if (bid < 264) {
    int idx = bid * 256 + (int)threadIdx.x;  // < 67584
    if (idx < 20480) {                       // W1: [128][160]
      int f = idx >> 9, r = idx & 511, L = r >> 3, j = r & 7;
      int t = f / 5, c = f - t * 5;
      int n = t * 16 + (L & 15), k = c * 32 + (L >> 4) * 8 + j;
      wsb[idx] = f2bf(W1[n * 160 + k]);
    } else if (idx < 36864) {                // W2: [128][128]
      int e = idx - 20480;
      int f = e >> 9, r = e & 511, L = r >> 3, j = r & 7;
      int t = f >> 2, c = f & 3;
      int n = t * 16 + (L & 15), k = c * 32 + (L >> 4) * 8 + j;
      wsb[idx] = f2bf(W2[n * 128 + k]);
    } else if (idx < 53248) {                // Wf: [128][128]
      int e = idx - 36864;
      int f = e >> 9, r = e & 511, L = r >> 3, j = r & 7;
      int t = f >> 2, c = f & 3;
      int n = t * 16 + (L & 15), k = c * 32 + (L >> 4) * 8 + j;
      wsb[idx] = f2bf(Wf[n * 128 + k]);
    } else {                                 // seen: [100->112][128]
      int e = idx - 53248;
      int f = e >> 9, r = e & 511, L = r >> 3, j = r & 7;
      int t = f >> 2, c = f & 3;
      int n = t * 16 + (L & 15), k = c * 32 + (L >> 4) * 8 + j;
      float v = (n < 100) ? seen[n * 128 + k] : 0.f;
      wsb[idx] = f2bf(v);
    }
  } else {                                   // s2: one wave per row
    int wv = (int)threadIdx.x >> 6, lane = (int)threadIdx.x & 63;
    int mm = (bid - 264) * 4 + wv;           // 0..111
    float s;
    if (mm < 100) {
      float v0 = seen[mm * 128 + lane], v1 = seen[mm * 128 + 64 + lane];
      s = v0 * v0 + v1 * v1;
#pragma unroll
      for (int msk = 1; msk < 64; msk <<= 1) s += __shfl_xor(s, msk, 64);
    } else {
      s = 1e30f;
    }
    if (lane == 0) s2[mm] = s;
  }
}

// pack two float4 (8 consecutive f32) into one bf16 A-fragment
__device__ __forceinline__ v8s cvt_frag(float4 lo, float4 hi) {
  union { v8s v; unsigned u[4]; } r;
  r.u[0] = f2bf2(lo.x, lo.y);
  r.u[1] = f2bf2(lo.z, lo.w);
  r.u[2] = f2bf2(hi.x, hi.y);
  r.u[3] = f2bf2(hi.z, hi.w);
  return r.v;
}

__device__ __forceinline__ v8s read_frag(const unsigned short* buf, int m, int q, int c) {
  return *(const v8s*)(buf + m * 136 + c * 32 + q * 8);
}
__device__ __forceinline__ v8s wfrag(const unsigned short* __restrict__ wsb,
                                     int base, int fragIdx, int lane) {
  return *(const v8s*)(wsb + base + fragIdx * 512 + lane * 8);
}

// async global->LDS, 16B per lane; dest is wave-uniform base + lane*16 (linear),
// source per-lane. wsb frag-linear layout == identity map both sides.
__device__ __forceinline__ void gload_lds16(const unsigned short* g, unsigned short* l) {
  __builtin_amdgcn_global_load_lds(
      (const __attribute__((address_space(1))) unsigned int*)g,
      (__attribute__((address_space(3))) unsigned int*)l, 16, 0, 0);
}

// epilogue: acc + bias (opt relu) -> bf16 -> s_int
__device__ __forceinline__ void epi_store(unsigned short* bufT, v4f acc, float bv,
                                          int q, int tg, int m, bool relu) {
#pragma unroll
  for (int r = 0; r < 4; r += 2) {
    float x0 = acc[r] + bv, x1 = acc[r + 1] + bv;
    if (relu) { x0 = fmaxf(x0, 0.f); x1 = fmaxf(x1, 0.f); }
    unsigned p = f2bf2(x0, x1);
    bufT[(q * 4 + r) * 136 + tg * 16 + m] = (unsigned short)p;
    bufT[(q * 4 + r + 1) * 136 + tg * 16 + m] = (unsigned short)(p >> 16);
  }
}
// fused fa/fp epilogue: fa -> bf16 -> s_int, a2s += fa^2, pe += (fp-fa)^2
__device__ __forceinline__ void epi_fafp(unsigned short* bufT, v4f fav, v4f fpv, float bv,
                                         int q, int tg, int m, float* a2sT, float* peT) {
#pragma unroll
  for (int rp = 0; rp < 2; ++rp) {
    int r = rp * 2;
    unsigned p = f2bf2(fmaxf(fav[r] + bv, 0.f), fmaxf(fav[r + 1] + bv, 0.f));
    bufT[(q * 4 + r) * 136 + tg * 16 + m] = (unsigned short)p;
    bufT[(q * 4 + r + 1) * 136 + tg * 16 + m] = (unsigned short)(p >> 16);
    float flo = bf2f((unsigned short)p), fhi = bf2f((unsigned short)(p >> 16));
    a2sT[r] += flo * flo;
    a2sT[r + 1] += fhi * fhi;
    float d0 = fmaxf(fpv[r] + bv, 0.f) - flo;
    float d1 = fmaxf(fpv[r + 1] + bv, 0.f) - fhi;
    peT[r] += d0 * d0;
    peT[r + 1] += d1 * d1;
  }
}

// PERSISTENT kernel: 256 blocks x 512 threads (8 waves), 1 block/CU (LDS 138KB).
// W1+W2+Wf (104KB) staged into LDS ONCE; then a barrier-free loop: each wave
// independently processes 8 x 16-row tiles (2048 waves x 8 x 16 = 262144 rows).
// Zero inter-wave sync in the loop; s_int transpose buffers are wave-private
// (in-wave DS ordering only). Next-iteration input bursts issued during the
// GEMM5 window; seen/s2 read from global (L1/L2-resident, 28KB).
__global__ __launch_bounds__(512, 2) void curiosity_main(
    const float* __restrict__ state, const float* __restrict__ action,
    const float* __restrict__ next_state,
    const float* __restrict__ b1, const float* __restrict__ b2,
    const float* __restrict__ bfv,
    const unsigned short* __restrict__ wsb, const float* __restrict__ s2g,
    float* __restrict__ out) {
  __shared__ __attribute__((aligned(16))) unsigned short s_wt[53248];   // 104 KB
  __shared__ __attribute__((aligned(16))) unsigned short s_int[8][2176]; // 34 KB

  const int tid = (int)threadIdx.x;
  const int w = tid >> 6, lane = tid & 63;
  const int m = lane & 15, q = lane >> 4;
  const int wave_gid = (int)blockIdx.x * 8 + w;   // 0..2047

  unsigned short* buf = &s_int[w][0];

  // ---- stage all W1/W2/Wf fragments once (13 frags/wave, 8 waves = 104)
#pragma unroll 1
  for (int i = w * 13; i < w * 13 + 13; ++i)
    gload_lds16(wsb + (size_t)i * 512 + lane * 8, s_wt + i * 512);

  // ---- loop-invariant per-lane scalars
  float bv1[8], bv2[8], bvf[8], s2v[7];
#pragma unroll
  for (int tg = 0; tg < 8; ++tg) bv1[tg] = b1[tg * 16 + m];
#pragma unroll
  for (int tg = 0; tg < 8; ++tg) bv2[tg] = b2[tg * 16 + m];
#pragma unroll
  for (int tg = 0; tg < 8; ++tg) bvf[tg] = bfv[tg * 16 + m];
#pragma unroll
  for (int tl = 0; tl < 7; ++tl) s2v[tl] = s2g[tl * 16 + m];

  // ---- iteration-0 input burst (18 dwordx4)
  const float* st = state + ((size_t)wave_gid * 16 + m) * 128 + q * 8;
  const float* ac = action + ((size_t)wave_gid * 16 + m) * 32 + q * 8;
  const float* np = next_state + ((size_t)wave_gid * 16 + m) * 128 + q * 8;
  const size_t stStep = (size_t)2048 * 16 * 128;
  const size_t acStep = (size_t)2048 * 16 * 32;

  float4 sv[4][2], av[2], nv[4][2];
#pragma unroll
  for (int c = 0; c < 4; ++c) {
    sv[c][0] = *(const float4*)(st + c * 32);
    sv[c][1] = *(const float4*)(st + c * 32 + 4);
  }
  av[0] = *(const float4*)(ac);
  av[1] = *(const float4*)(ac + 4);
#pragma unroll
  for (int c = 0; c < 4; ++c) {
    nv[c][0] = *(const float4*)(np + c * 32);
    nv[c][1] = *(const float4*)(np + c * 32 + 4);
  }

  __syncthreads();   // weights staged (and our burst drained)

  int T = wave_gid;
#pragma unroll 1
  for (int it = 0; it < 8; ++it) {
    // ---- convert current payloads to bf16 A-fragments
    v8s a1[5], a3[4];
#pragma unroll
    for (int c = 0; c < 4; ++c) a1[c] = cvt_frag(sv[c][0], sv[c][1]);
    a1[4] = cvt_frag(av[0], av[1]);
#pragma unroll
    for (int c = 0; c < 4; ++c) a3[c] = cvt_frag(nv[c][0], nv[c][1]);

    // ---- GEMM1: h = relu(x @ W1^T + b1)
#pragma unroll
    for (int tf = 0; tf < 8; ++tf) {
      v8s bfr[5];
#pragma unroll
      for (int c = 0; c < 5; ++c)
        bfr[c] = *(const v8s*)(s_wt + WS_W1 + (tf * 5 + c) * 512 + lane * 8);
      v4f acc = {};
#pragma unroll
      for (int c = 0; c < 5; ++c) acc = MFMA(a1[c], bfr[c], acc, 0, 0, 0);
      epi_store(buf, acc, bv1[tf], q, tf, m, true);
    }

    // ---- GEMM2: pn = h @ W2^T + b2
    v8s af[4];
#pragma unroll
    for (int c = 0; c < 4; ++c) af[c] = read_frag(buf, m, q, c);
#pragma unroll
    for (int tf = 0; tf < 8; ++tf) {
      v8s bfr[4];
#pragma unroll
      for (int c = 0; c < 4; ++c)
        bfr[c] = *(const v8s*)(s_wt + WS_W2 + (tf * 4 + c) * 512 + lane * 8);
      v4f acc = {};
#pragma unroll
      for (int c = 0; c < 4; ++c) acc = MFMA(af[c], bfr[c], acc, 0, 0, 0);
      epi_store(buf, acc, bv2[tf], q, tf, m, false);
    }

    // ---- seen batch1 (tl 0..3) issued; L1/L2-resident, covered by GEMM3/4
    v8s sg1[16];
#pragma unroll
    for (int i = 0; i < 16; ++i) sg1[i] = wfrag(wsb, WS_SEEN, i, lane);

    // ---- fused GEMM3+GEMM4: fa = relu(ns@Wf^T+bf), fp = relu(pn@Wf^T+bf)
    v8s a4[4];
#pragma unroll
    for (int c = 0; c < 4; ++c) a4[c] = read_frag(buf, m, q, c);
    float pe[4] = {}, a2s[4] = {};
#pragma unroll
    for (int tf = 0; tf < 8; ++tf) {
      v8s bfr[4];
#pragma unroll
      for (int c = 0; c < 4; ++c)
        bfr[c] = *(const v8s*)(s_wt + WS_WF + (tf * 4 + c) * 512 + lane * 8);
      v4f fa = {}, fp = {};
#pragma unroll
      for (int c = 0; c < 4; ++c) {
        fa = MFMA(a3[c], bfr[c], fa, 0, 0, 0);
        fp = MFMA(a4[c], bfr[c], fp, 0, 0, 0);
      }
      epi_fafp(buf, fa, fp, bvf[tf], q, tf, m, a2s, pe);
    }

    // ---- seen batch2 + next-iteration input bursts (drain by next-iter cvt)
    v8s sg2[12];
#pragma unroll
    for (int i = 0; i < 12; ++i) sg2[i] = wfrag(wsb, WS_SEEN, 16 + i, lane);
    if (it != 7) {
      st += stStep; ac += acStep; np += stStep;
#pragma unroll
      for (int c = 0; c < 4; ++c) {
        sv[c][0] = *(const float4*)(st + c * 32);
        sv[c][1] = *(const float4*)(st + c * 32 + 4);
      }
      av[0] = *(const float4*)(ac);
      av[1] = *(const float4*)(ac + 4);
#pragma unroll
      for (int c = 0; c < 4; ++c) {
        nv[c][0] = *(const float4*)(np + c * 32);
        nv[c][1] = *(const float4*)(np + c * 32 + 4);
      }
    }

    // ---- reduce pe / ||fa||^2 across the 16 feature-lanes
#pragma unroll
    for (int r = 0; r < 4; ++r)
#pragma unroll
      for (int msk = 1; msk < 16; msk <<= 1) {
        pe[r] += __shfl_xor(pe[r], msk, 16);
        a2s[r] += __shfl_xor(a2s[r], msk, 16);
      }

    // ---- GEMM5: g = fa @ seen^T; d2 = a2 + s2 - 2g
    v8s a5[4];
#pragma unroll
    for (int c = 0; c < 4; ++c) a5[c] = read_frag(buf, m, q, c);
    float dmin[4] = {3.4e38f, 3.4e38f, 3.4e38f, 3.4e38f};
#pragma unroll
    for (int tl = 0; tl < 7; ++tl) {
      const v8s* sp = (tl < 4) ? (sg1 + tl * 4) : (sg2 + (tl - 4) * 4);
      v4f g = {};
#pragma unroll
      for (int c = 0; c < 4; ++c) g = MFMA(a5[c], sp[c], g, 0, 0, 0);
      float s2x = s2v[tl];
#pragma unroll
      for (int r = 0; r < 4; ++r)
        dmin[r] = fminf(dmin[r], a2s[r] + s2x - 2.f * g[r]);
    }
#pragma unroll
    for (int r = 0; r < 4; ++r)
#pragma unroll
      for (int msk = 1; msk < 16; msk <<= 1)
        dmin[r] = fminf(dmin[r], __shfl_xor(dmin[r], msk, 16));

    // ---- outputs: rows T*16 + q*4 + r, written by the m==0 lanes
    if (m == 0) {
#pragma unroll
      for (int r = 0; r < 4; ++r) {
        size_t rb = (size_t)T * 16 + q * 4 + r;
        float p = pe[r] * (1.f / 128.f);
        float nov = fminf(1.f, sqrtf(fmaxf(dmin[r], 0.f)) * 0.1f);
        out[rb] = p;
        out[(size_t)B_TOT + rb] = nov;
        out[2 * (size_t)B_TOT + rb] = 0.5f * (p + nov);
      }
    }
    T += 2048;
  }
}

extern "C" void kernel_launch(void* const* d_in, const int* in_sizes, int n_in,
                              void* d_out, int out_size, void* d_ws, size_t ws_size,
                              hipStream_t stream) {
  const float* state      = (const float*)d_in[0];
  const float* action     = (const float*)d_in[1];
  const float* next_state = (const float*)d_in[2];
  const float* seen       = (const float*)d_in[3];
  const float* W1         = (const float*)d_in[4];
  const float* b1         = (const float*)d_in[5];
  const float* W2         = (const float*)d_in[6];
  const float* b2         = (const float*)d_in[7];
  const float* Wf         = (const float*)d_in[8];
  const float* bf_        = (const float*)d_in[9];

  unsigned short* wsb = (unsigned short*)d_ws;
  float* s2 = (float*)((char*)d_ws + WS_S2_BYTES);

  curiosity_prep<<<292, 256, 0, stream>>>(W1, W2, Wf, seen, wsb, s2);
  curiosity_main<<<256, 512, 0, stream>>>(state, action, next_state, b1, b2, bf_,
                                          wsb, s2, (float*)d_out);
}

// Round 6
// 321.246 us; speedup vs baseline: 1.5005x; 1.5005x over previous
//
#include <hip/hip_runtime.h>
#include <hip/hip_bf16.h>
#include <math.h>

#define B_TOT 262144

typedef __attribute__((ext_vector_type(8))) short v8s;
typedef __attribute__((ext_vector_type(4))) float v4f;

// ws layout (bf16 element offsets):
//  W1 frag-order   [0, 20480)        (8 n-tiles x 5 k-chunks x 512)
//  W2 frag-order   [20480, 36864)    (8 x 4 x 512)
//  Wf frag-order   [36864, 53248)    (8 x 4 x 512)
//  seen frag-order [53248, 67584)    (7 x 4 x 512, rows >=100 zero-padded)
//  s2 (fp32)       byte offset 135168, 112 floats (1e30 for pad rows)
#define WS_W1 0
#define WS_W2 20480
#define WS_WF 36864
#define WS_SEEN 53248
#define WS_S2_BYTES 135168

#define MFMA __builtin_amdgcn_mfma_f32_16x16x32_bf16

__device__ __forceinline__ unsigned short f2bf(float f) {
  union { float f; unsigned u; } cv; cv.f = f;
  unsigned u = cv.u;
  return (unsigned short)((u + 0x7FFFu + ((u >> 16) & 1u)) >> 16);  // RNE
}
__device__ __forceinline__ float bf2f(unsigned short h) {
  union { unsigned u; float f; } cv; cv.u = ((unsigned)h) << 16;
  return cv.f;
}
// packed RNE f32x2 -> bf16x2 (v_cvt_pk_bf16_f32 on gfx950); low 16 = x
__device__ __forceinline__ unsigned f2bf2(float x, float y) {
  float2 f; f.x = x; f.y = y;
  __hip_bfloat162 h = __float22bfloat162_rn(f);
  union { __hip_bfloat162 h; unsigned u; } cv; cv.h = h;
  return cv.u;
}

// Repack weights to bf16 in MFMA B-fragment-linear order.
// B-frag for (tile t, k-chunk c): lane L holds B[n = t*16 + (L&15)][k = c*32 + (L>>4)*8 + j]
__global__ void curiosity_prep(const float* __restrict__ W1, const float* __restrict__ W2,
                               const float* __restrict__ Wf, const float* __restrict__ seen,
                               unsigned short* __restrict__ wsb, float* __restrict__ s2) {
  int bid = blockIdx.x;
  if (bid < 264) {
    int idx = bid * 256 + (int)threadIdx.x;  // < 67584
    if (idx < 20480) {                       // W1: [128][160]
      int f = idx >> 9, r = idx & 511, L = r >> 3, j = r & 7;
      int t = f / 5, c = f - t * 5;
      int n = t * 16 + (L & 15), k = c * 32 + (L >> 4) * 8 + j;
      wsb[idx] = f2bf(W1[n * 160 + k]);
    } else if (idx < 36864) {                // W2: [128][128]
      int e = idx - 20480;
      int f = e >> 9, r = e & 511, L = r >> 3, j = r & 7;
      int t = f >> 2, c = f & 3;
      int n = t * 16 + (L & 15), k = c * 32 + (L >> 4) * 8 + j;
      wsb[idx] = f2bf(W2[n * 128 + k]);
    } else if (idx < 53248) {                // Wf: [128][128]
      int e = idx - 36864;
      int f = e >> 9, r = e & 511, L = r >> 3, j = r & 7;
      int t = f >> 2, c = f & 3;
      int n = t * 16 + (L & 15), k = c * 32 + (L >> 4) * 8 + j;
      wsb[idx] = f2bf(Wf[n * 128 + k]);
    } else {                                 // seen: [100->112][128]
      int e = idx - 53248;
      int f = e >> 9, r = e & 511, L = r >> 3, j = r & 7;
      int t = f >> 2, c = f & 3;
      int n = t * 16 + (L & 15), k = c * 32 + (L >> 4) * 8 + j;
      float v = (n < 100) ? seen[n * 128 + k] : 0.f;
      wsb[idx] = f2bf(v);
    }
  } else {                                   // s2: one wave per row
    int wv = (int)threadIdx.x >> 6, lane = (int)threadIdx.x & 63;
    int mm = (bid - 264) * 4 + wv;           // 0..111
    float s;
    if (mm < 100) {
      float v0 = seen[mm * 128 + lane], v1 = seen[mm * 128 + 64 + lane];
      s = v0 * v0 + v1 * v1;
#pragma unroll
      for (int msk = 1; msk < 64; msk <<= 1) s += __shfl_xor(s, msk, 64);
    } else {
      s = 1e30f;
    }
    if (lane == 0) s2[mm] = s;
  }
}

// pack two float4 (8 consecutive f32) into one bf16 A-fragment
__device__ __forceinline__ v8s cvt_frag(float4 lo, float4 hi) {
  union { v8s v; unsigned u[4]; } r;
  r.u[0] = f2bf2(lo.x, lo.y);
  r.u[1] = f2bf2(lo.z, lo.w);
  r.u[2] = f2bf2(hi.x, hi.y);
  r.u[3] = f2bf2(hi.z, hi.w);
  return r.v;
}

__device__ __forceinline__ v8s read_frag(const unsigned short* buf, int m, int q, int c) {
  return *(const v8s*)(buf + m * 136 + c * 32 + q * 8);
}

// async global->LDS, 16B per lane; dest is wave-uniform base + lane*16 (linear),
// source per-lane. wsb frag-linear layout == identity map both sides.
__device__ __forceinline__ void gload_lds16(const unsigned short* g, unsigned short* l) {
  __builtin_amdgcn_global_load_lds(
      (const __attribute__((address_space(1))) unsigned int*)g,
      (__attribute__((address_space(3))) unsigned int*)l, 16, 0, 0);
}
template <int N>
__device__ __forceinline__ void stage_frags(const unsigned short* __restrict__ g,
                                            unsigned short* l, int f0, int lane) {
#pragma unroll
  for (int i = 0; i < N; ++i)
    gload_lds16(g + (size_t)(f0 + i) * 512 + lane * 8, l + (size_t)(f0 + i) * 512);
}
__device__ __forceinline__ v8s sfrag(const unsigned short* s_wt, int frag, int lane) {
  return *(const v8s*)(s_wt + frag * 512 + lane * 8);
}

// 4096 blocks x 256 threads; 4 waves/block; each wave owns ONE 16-row tile.
// R2's proven coarse structure (stage whole weight region -> barrier -> big
// compute) and live-range placement, with the per-wave tile halved so LDS =
// 32 (stage) + 17 (s_int) + 0.75 (s_o) = 49.8 KB -> 3 blocks/CU, and peak
// register demand ~halved so launch_bounds(256,3)'s 168-VGPR target has
// ample headroom (no spills -- WRITE_SIZE is the tripwire).
__global__ __launch_bounds__(256, 3) void curiosity_main(
    const float* __restrict__ state, const float* __restrict__ action,
    const float* __restrict__ next_state,
    const float* __restrict__ b1, const float* __restrict__ b2,
    const float* __restrict__ bfv,
    const unsigned short* __restrict__ wsb, const float* __restrict__ s2g,
    float* __restrict__ out) {
  __shared__ __attribute__((aligned(16))) unsigned short s_wt[16384];    // 32 KB
  __shared__ __attribute__((aligned(16))) unsigned short s_int[4][2176]; // 17 KB
  __shared__ float s_o[3][64];

  const int tid = (int)threadIdx.x;
  const int w = tid >> 6, lane = tid & 63;
  const int m = lane & 15, q = lane >> 4;
  const int rowblk = (int)blockIdx.x * 64 + w * 16;

  unsigned short* buf = &s_int[w][0];

  const float* st0 = state + (size_t)(rowblk + m) * 128 + q * 8;
  const float* ac0 = action + (size_t)(rowblk + m) * 32 + q * 8;
  const float* np0 = next_state + (size_t)(rowblk + m) * 128 + q * 8;

  // ---- prologue: state+action burst (10 dwordx4) + stage W1 hf0 + b1, one
  //      latency window drained by a single barrier.
  float4 sv[4][2], av[2];
#pragma unroll
  for (int c = 0; c < 4; ++c) {
    sv[c][0] = *(const float4*)(st0 + c * 32);
    sv[c][1] = *(const float4*)(st0 + c * 32 + 4);
  }
  av[0] = *(const float4*)(ac0);
  av[1] = *(const float4*)(ac0 + 4);
  stage_frags<5>(wsb + WS_W1, s_wt, w * 5, lane);
  float bv1[8];
#pragma unroll
  for (int tg = 0; tg < 8; ++tg) bv1[tg] = b1[tg * 16 + m];

  // convert while stage drains
  v8s a1[5];
#pragma unroll
  for (int c = 0; c < 4; ++c) a1[c] = cvt_frag(sv[c][0], sv[c][1]);
  a1[4] = cvt_frag(av[0], av[1]);
  __syncthreads();                      // W1 hf0 staged

  // ---- GEMM1: h = relu(x @ W1^T + b1); two stage phases (W1 = 40KB)
#pragma unroll
  for (int hf = 0; hf < 2; ++hf) {
    if (hf == 1) {
      __syncthreads();                                   // hf0 frag reads done
      stage_frags<5>(wsb + WS_W1 + 20 * 512, s_wt, w * 5, lane);
      __syncthreads();                                   // hf1 staged
    }
    v8s bfr[20];
#pragma unroll
    for (int c = 0; c < 5; ++c)
#pragma unroll
      for (int tl = 0; tl < 4; ++tl)
        bfr[c * 4 + tl] = sfrag(s_wt, tl * 5 + c, lane);
    v4f acc[4] = {};
#pragma unroll
    for (int c = 0; c < 5; ++c)
#pragma unroll
      for (int tl = 0; tl < 4; ++tl)
        acc[tl] = MFMA(a1[c], bfr[c * 4 + tl], acc[tl], 0, 0, 0);
#pragma unroll
    for (int tl = 0; tl < 4; ++tl) {
      int tg = hf * 4 + tl;
      float bv = bv1[tg];
#pragma unroll
      for (int r = 0; r < 4; r += 2) {
        unsigned p = f2bf2(fmaxf(acc[tl][r] + bv, 0.f),
                           fmaxf(acc[tl][r + 1] + bv, 0.f));
        buf[(q * 4 + r) * 136 + tg * 16 + m] = (unsigned short)p;
        buf[(q * 4 + r + 1) * 136 + tg * 16 + m] = (unsigned short)(p >> 16);
      }
    }
  }

  // ---- stage W2 whole (32 frags); slot af reads + bias loads under barrier
  __syncthreads();
  stage_frags<8>(wsb + WS_W2, s_wt, w * 8, lane);
  float bv2[8];
#pragma unroll
  for (int tg = 0; tg < 8; ++tg) bv2[tg] = b2[tg * 16 + m];
  v8s af[4];
#pragma unroll
  for (int c = 0; c < 4; ++c) af[c] = read_frag(buf, m, q, c);
  __syncthreads();

  // ---- next_state burst issued here (R2 placement); drains at the Wf-phase
  //      barrier, hidden under GEMM2 compute; converted at GEMM3 entry.
  float4 nv[4][2];
#pragma unroll
  for (int c = 0; c < 4; ++c) {
    nv[c][0] = *(const float4*)(np0 + c * 32);
    nv[c][1] = *(const float4*)(np0 + c * 32 + 4);
  }

  // ---- GEMM2: pn = h @ W2^T + b2
#pragma unroll
  for (int hf = 0; hf < 2; ++hf) {
    v8s bfr[16];
#pragma unroll
    for (int c = 0; c < 4; ++c)
#pragma unroll
      for (int tl = 0; tl < 4; ++tl)
        bfr[c * 4 + tl] = sfrag(s_wt, (hf * 4 + tl) * 4 + c, lane);
    v4f acc[4] = {};
#pragma unroll
    for (int c = 0; c < 4; ++c)
#pragma unroll
      for (int tl = 0; tl < 4; ++tl)
        acc[tl] = MFMA(af[c], bfr[c * 4 + tl], acc[tl], 0, 0, 0);
#pragma unroll
    for (int tl = 0; tl < 4; ++tl) {
      int tg = hf * 4 + tl;
      float bv = bv2[tg];
#pragma unroll
      for (int r = 0; r < 4; r += 2) {
        unsigned p = f2bf2(acc[tl][r] + bv, acc[tl][r + 1] + bv);
        buf[(q * 4 + r) * 136 + tg * 16 + m] = (unsigned short)p;
        buf[(q * 4 + r + 1) * 136 + tg * 16 + m] = (unsigned short)(p >> 16);
      }
    }
  }

  // ---- stage Wf whole; slot a4 (pn) reads + bias under barrier
  __syncthreads();
  stage_frags<8>(wsb + WS_WF, s_wt, w * 8, lane);
  float bvf[8];
#pragma unroll
  for (int tg = 0; tg < 8; ++tg) bvf[tg] = bfv[tg * 16 + m];
  v8s a4[4];
#pragma unroll
  for (int c = 0; c < 4; ++c) a4[c] = read_frag(buf, m, q, c);
  __syncthreads();   // also drains the next_state burst

  v8s a3[4];
#pragma unroll
  for (int c = 0; c < 4; ++c) a3[c] = cvt_frag(nv[c][0], nv[c][1]);

  // ---- fused GEMM3+GEMM4: fa = relu(ns @ Wf^T + bf), fp = relu(pn @ Wf^T + bf)
  float pe[4] = {};
  float a2s[4] = {};
#pragma unroll
  for (int hf = 0; hf < 2; ++hf) {
    v8s bfr[16];
#pragma unroll
    for (int tl = 0; tl < 4; ++tl)
#pragma unroll
      for (int c = 0; c < 4; ++c)
        bfr[tl * 4 + c] = sfrag(s_wt, (hf * 4 + tl) * 4 + c, lane);
#pragma unroll
    for (int tl = 0; tl < 4; ++tl) {
      v4f fa = {}, fp = {};
#pragma unroll
      for (int c = 0; c < 4; ++c) {
        fa = MFMA(a3[c], bfr[tl * 4 + c], fa, 0, 0, 0);
        fp = MFMA(a4[c], bfr[tl * 4 + c], fp, 0, 0, 0);
      }
      int tg = hf * 4 + tl;
      float bv = bvf[tg];
#pragma unroll
      for (int rp = 0; rp < 2; ++rp) {
        int r = rp * 2;
        unsigned p = f2bf2(fmaxf(fa[r] + bv, 0.f), fmaxf(fa[r + 1] + bv, 0.f));
        buf[(q * 4 + r) * 136 + tg * 16 + m] = (unsigned short)p;
        buf[(q * 4 + r + 1) * 136 + tg * 16 + m] = (unsigned short)(p >> 16);
        float flo = bf2f((unsigned short)p), fhi = bf2f((unsigned short)(p >> 16));
        a2s[r] += flo * flo;
        a2s[r + 1] += fhi * fhi;
        float d0 = fmaxf(fp[r] + bv, 0.f) - flo;
        float d1 = fmaxf(fp[r + 1] + bv, 0.f) - fhi;
        pe[r] += d0 * d0;
        pe[r + 1] += d1 * d1;
      }
    }
  }

  // ---- stage seen; hide its latency under the pe/a2s shuffle reduce + a5 reads
  __syncthreads();
  stage_frags<7>(wsb + WS_SEEN, s_wt, w * 7, lane);
  float s2v[7];
#pragma unroll
  for (int tl = 0; tl < 7; ++tl) s2v[tl] = s2g[tl * 16 + m];
#pragma unroll
  for (int r = 0; r < 4; ++r)
#pragma unroll
    for (int msk = 1; msk < 16; msk <<= 1) {
      pe[r] += __shfl_xor(pe[r], msk, 16);
      a2s[r] += __shfl_xor(a2s[r], msk, 16);
    }
  v8s a5[4];
#pragma unroll
  for (int c = 0; c < 4; ++c) a5[c] = read_frag(buf, m, q, c);
  __syncthreads();

  // ---- GEMM5: g = fa @ seen^T (N=112 incl pad), d2 = a2 + s2 - 2g
  float dmin[4] = {3.4e38f, 3.4e38f, 3.4e38f, 3.4e38f};
  {
    v8s bfr[16];
#pragma unroll
    for (int tl = 0; tl < 4; ++tl)
#pragma unroll
      for (int c = 0; c < 4; ++c)
        bfr[tl * 4 + c] = sfrag(s_wt, tl * 4 + c, lane);
#pragma unroll
    for (int tl = 0; tl < 4; ++tl) {
      v4f g = {};
#pragma unroll
      for (int c = 0; c < 4; ++c) g = MFMA(a5[c], bfr[tl * 4 + c], g, 0, 0, 0);
      float s2x = s2v[tl];
#pragma unroll
      for (int r = 0; r < 4; ++r)
        dmin[r] = fminf(dmin[r], a2s[r] + s2x - 2.f * g[r]);
    }
  }
  {
    v8s bfr[12];
#pragma unroll
    for (int tl = 0; tl < 3; ++tl)
#pragma unroll
      for (int c = 0; c < 4; ++c)
        bfr[tl * 4 + c] = sfrag(s_wt, (tl + 4) * 4 + c, lane);
#pragma unroll
    for (int tl = 0; tl < 3; ++tl) {
      v4f g = {};
#pragma unroll
      for (int c = 0; c < 4; ++c) g = MFMA(a5[c], bfr[tl * 4 + c], g, 0, 0, 0);
      float s2x = s2v[tl + 4];
#pragma unroll
      for (int r = 0; r < 4; ++r)
        dmin[r] = fminf(dmin[r], a2s[r] + s2x - 2.f * g[r]);
    }
  }
#pragma unroll
  for (int r = 0; r < 4; ++r)
#pragma unroll
    for (int msk = 1; msk < 16; msk <<= 1)
      dmin[r] = fminf(dmin[r], __shfl_xor(dmin[r], msk, 16));

  if (m == 0) {
#pragma unroll
    for (int r = 0; r < 4; ++r) {
      int rl = w * 16 + q * 4 + r;
      float p = pe[r] * (1.f / 128.f);
      float nov = fminf(1.f, sqrtf(fmaxf(dmin[r], 0.f)) * 0.1f);
      s_o[0][rl] = p;
      s_o[1][rl] = nov;
      s_o[2][rl] = 0.5f * (p + nov);
    }
  }
  __syncthreads();
  const size_t base = (size_t)blockIdx.x * 64;
  if (tid < 192) {
    int j = tid >> 6, r = tid & 63;
    out[(size_t)j * B_TOT + base + r] = s_o[j][r];
  }
}

extern "C" void kernel_launch(void* const* d_in, const int* in_sizes, int n_in,
                              void* d_out, int out_size, void* d_ws, size_t ws_size,
                              hipStream_t stream) {
  const float* state      = (const float*)d_in[0];
  const float* action     = (const float*)d_in[1];
  const float* next_state = (const float*)d_in[2];
  const float* seen       = (const float*)d_in[3];
  const float* W1         = (const float*)d_in[4];
  const float* b1         = (const float*)d_in[5];
  const float* W2         = (const float*)d_in[6];
  const float* b2         = (const float*)d_in[7];
  const float* Wf         = (const float*)d_in[8];
  const float* bf_        = (const float*)d_in[9];

  unsigned short* wsb = (unsigned short*)d_ws;
  float* s2 = (float*)((char*)d_ws + WS_S2_BYTES);

  curiosity_prep<<<292, 256, 0, stream>>>(W1, W2, Wf, seen, wsb, s2);
  curiosity_main<<<4096, 256, 0, stream>>>(state, action, next_state, b1, b2, bf_,
                                           wsb, s2, (float*)d_out);
}